// Round 12
// baseline (267.216 us; speedup 1.0000x reference)
//
#include <hip/hip_runtime.h>
#include <hip/hip_bf16.h>
#include <string.h>

#define OUT_H 7
#define OUT_W 7
#define FEAT_H 200
#define FEAT_W 200
#define HW_ALL (FEAT_H * FEAT_W)
#define THW 160          // hw per transpose tile (40000 % 160 == 0 -> 250 tiles)
#define TLS 161          // LDS row stride (floats); 161%32==1 -> ~2-way conflicts max

__device__ inline unsigned pack2_bf16(float a, float b) {
    __hip_bfloat16 ha = __float2bfloat16(a);
    __hip_bfloat16 hb = __float2bfloat16(b);
    unsigned short ua, ub;
    memcpy(&ua, &ha, 2);
    memcpy(&ub, &hb, 2);
    return (unsigned)ua | ((unsigned)ub << 16);
}

// ---------------- Kernel 1: NCHW fp32 -> blocked-NHWC bf16 (v4, measured-good) ----
__global__ __launch_bounds__(256) void nchw_to_blocked_v4(
    const float* __restrict__ feat,   // (B, 256, HW)
    uint2*       __restrict__ featT,  // (B, 4, HW, 16) uint2 (=64ch bf16)
    int HW)
{
    __shared__ float tile[64 * TLS];     // 41.2 KB -> 3 blocks/CU
    int hw0 = blockIdx.x * THW;
    int cg  = blockIdx.y;                // channel group 0..3
    int b   = blockIdx.z;
    const float* src = feat + ((size_t)b * 256 + cg * 64) * HW + hw0;
    int t = threadIdx.x;

#pragma unroll
    for (int i = 0; i < 10; ++i) {
        int flat = i * 256 + t;          // 0..2559
        int c = flat / 40;               // channel 0..63
        int q = flat % 40;               // float4 index within 160-hw run
        float4 v = *(const float4*)(src + (size_t)c * HW + q * 4);
        float* d = &tile[c * TLS + q * 4];
        d[0] = v.x; d[1] = v.y; d[2] = v.z; d[3] = v.w;
    }
    __syncthreads();

    uint2* dst = featT + ((size_t)(b * 4 + cg) * HW + hw0) * 16;
#pragma unroll
    for (int i = 0; i < 10; ++i) {
        int o  = i * 256 + t;            // 0..2559, == hw*16 + cq
        int hw = o >> 4;
        int cq = o & 15;                 // channels cq*4 .. cq*4+3
        float a0 = tile[(cq * 4 + 0) * TLS + hw];
        float a1 = tile[(cq * 4 + 1) * TLS + hw];
        float a2 = tile[(cq * 4 + 2) * TLS + hw];
        float a3 = tile[(cq * 4 + 3) * TLS + hw];
        uint2 u;
        u.x = pack2_bf16(a0, a1);
        u.y = pack2_bf16(a2, a3);
        dst[o] = u;
    }
}

// ---------------- Kernel 2: RoIAlign on blocked-NHWC bf16 (v4) ----------------
__global__ __launch_bounds__(256) void roialign_blocked_v4(
    const uint2* __restrict__ featT,   // (B, 4, HW, 16) uint2
    const int*   __restrict__ rois,    // (N, 5)
    float*       __restrict__ out)     // (N, 256, 49)
{
    __shared__ float acc[64 * OUT_H * OUT_W];    // 12.5 KB
    const int H = FEAT_H, W = FEAT_W;
    int n  = blockIdx.x >> 2;
    int cg = blockIdx.x & 3;
    const int* r = rois + n * 5;
    int   b   = r[0];
    float x1f = (float)r[1];
    float y1f = (float)r[2];
    float dx  = (float)r[3] - x1f;
    float dy  = (float)r[4] - y1f;

    int t  = threadIdx.x;
    int cq = t & 15;
    int pg = t >> 4;                     // 0..15
    const uint2* fb = featT + ((size_t)(b * 4 + cg) * HW_ALL) * 16 + cq;

#define BFLO(u) __uint_as_float((u) << 16)
#define BFHI(u) __uint_as_float((u) & 0xffff0000u)

#pragma unroll
    for (int pi = 0; pi < 4; ++pi) {
        int p = (pi << 4) + pg;
        if (p < 49) {
            int jy = p / 7, jx = p % 7;
            float sy = y1f + ((float)jy * dy) / 6.0f;
            float sx = x1f + ((float)jx * dx) / 6.0f;
            float y0fl = floorf(sy), x0fl = floorf(sx);
            float wy = sy - y0fl,    wx = sx - x0fl;
            int y0  = min(max((int)y0fl, 0), H - 1);
            int y1i = min(y0 + 1, H - 1);
            int x0  = min(max((int)x0fl, 0), W - 1);
            int x1i = min(x0 + 1, W - 1);
            float omwy = 1.0f - wy, omwx = 1.0f - wx;
            float w00 = omwy * omwx, w01 = omwy * wx;
            float w10 = wy * omwx,   w11 = wy * wx;

            uint2 u00 = fb[(size_t)(y0  * W + x0 ) * 16];
            uint2 u01 = fb[(size_t)(y0  * W + x1i) * 16];
            uint2 u10 = fb[(size_t)(y1i * W + x0 ) * 16];
            uint2 u11 = fb[(size_t)(y1i * W + x1i) * 16];

            float r0 = BFLO(u00.x)*w00 + BFLO(u01.x)*w01 + BFLO(u10.x)*w10 + BFLO(u11.x)*w11;
            float r1 = BFHI(u00.x)*w00 + BFHI(u01.x)*w01 + BFHI(u10.x)*w10 + BFHI(u11.x)*w11;
            float r2 = BFLO(u00.y)*w00 + BFLO(u01.y)*w01 + BFLO(u10.y)*w10 + BFLO(u11.y)*w11;
            float r3 = BFHI(u00.y)*w00 + BFHI(u01.y)*w01 + BFHI(u10.y)*w10 + BFHI(u11.y)*w11;

            int c0 = cq << 2;            // local channel base 0..60
            acc[(c0 + 0) * 49 + p] = r0;
            acc[(c0 + 1) * 49 + p] = r1;
            acc[(c0 + 2) * 49 + p] = r2;
            acc[(c0 + 3) * 49 + p] = r3;
        }
    }
    __syncthreads();

    float* ob = out + ((size_t)n * 256 + cg * 64) * (OUT_H * OUT_W);
    const int total = 64 * OUT_H * OUT_W;
    for (int k = t; k < total; k += 256)
        ob[k] = acc[k];
}

// ---------------- Fallback: direct NCHW gather ----------------
__global__ __launch_bounds__(256) void roialign_direct(
    const float* __restrict__ feat, const int* __restrict__ rois,
    float* __restrict__ out, int C, int H, int W, int total)
{
    int idx = blockIdx.x * blockDim.x + threadIdx.x;
    if (idx >= total) return;
    int jx = idx % OUT_W;
    int t  = idx / OUT_W;
    int jy = t % OUT_H;
    t /= OUT_H;
    int c = t % C;
    int n = t / C;
    const int* r = rois + n * 5;
    int b = r[0];
    float x1 = (float)r[1], y1 = (float)r[2];
    float x2 = (float)r[3], y2 = (float)r[4];
    float sy = y1 + ((float)jy * (y2 - y1)) / (float)(OUT_H - 1);
    float sx = x1 + ((float)jx * (x2 - x1)) / (float)(OUT_W - 1);
    float y0f = floorf(sy), x0f = floorf(sx);
    float wy = sy - y0f, wx = sx - x0f;
    int y0  = min(max((int)y0f, 0), H - 1);
    int y1i = min(y0 + 1, H - 1);
    int x0  = min(max((int)x0f, 0), W - 1);
    int x1i = min(x0 + 1, W - 1);
    const float* fp = feat + ((size_t)b * C + c) * (size_t)(H * W);
    float v00 = fp[y0  * W + x0 ];
    float v01 = fp[y0  * W + x1i];
    float v10 = fp[y1i * W + x0 ];
    float v11 = fp[y1i * W + x1i];
    float omwy = 1.0f - wy, omwx = 1.0f - wx;
    out[idx] = v00 * omwy * omwx + v01 * omwy * wx
             + v10 * wy   * omwx + v11 * wy   * wx;
}

extern "C" void kernel_launch(void* const* d_in, const int* in_sizes, int n_in,
                              void* d_out, int out_size, void* d_ws, size_t ws_size,
                              hipStream_t stream)
{
    const float* feat = (const float*)d_in[0];
    const int*   rois = (const int*)d_in[1];
    float*       out  = (float*)d_out;

    int N  = in_sizes[1] / 5;                        // 512
    int C  = out_size / (N * OUT_H * OUT_W);         // 256
    int B  = in_sizes[0] / (C * HW_ALL);             // 4 when geometry matches

    size_t need = (size_t)B * HW_ALL * 256 * sizeof(__hip_bfloat16);  // 82 MB
    if (C == 256 && in_sizes[0] == B * 256 * HW_ALL && ws_size >= need) {
        uint2* featT = (uint2*)d_ws;
        dim3 tgrid(HW_ALL / THW, 4, B);              // 250 x 4 x B
        nchw_to_blocked_v4<<<tgrid, 256, 0, stream>>>(feat, featT, HW_ALL);
        // ATTRIBUTION EXPERIMENT: launch align twice (idempotent — identical
        // output values). dur_delta vs round-9 baseline == cost of one align
        // dispatch (A). T = 96us - A decides the next optimization target.
        roialign_blocked_v4<<<N * 4, 256, 0, stream>>>(featT, rois, out);
        roialign_blocked_v4<<<N * 4, 256, 0, stream>>>(featT, rois, out);
    } else {
        int total = out_size;
        roialign_direct<<<(total + 255) / 256, 256, 0, stream>>>(
            feat, rois, out, C, FEAT_H, FEAT_W, total);
    }
}

// Round 14
// 263.778 us; speedup vs baseline: 1.0130x; 1.0130x over previous
//
#include <hip/hip_runtime.h>
#include <hip/hip_bf16.h>
#include <string.h>

#define OUT_H 7
#define OUT_W 7
#define FEAT_H 200
#define FEAT_W 200
#define HW_ALL (FEAT_H * FEAT_W)
#define TPW 17           // LDS floats per channel row (stride pad; 17 coprime 32)

__device__ inline unsigned pack2_bf16(float a, float b) {
    __hip_bfloat16 ha = __float2bfloat16(a);
    __hip_bfloat16 hb = __float2bfloat16(b);
    unsigned short ua, ub;
    memcpy(&ua, &ha, 2);
    memcpy(&ub, &hb, 2);
    return (unsigned)ua | ((unsigned)ub << 16);
}

// ---------------- Kernel 1 (v5): NCHW fp32 -> blocked-NHWC bf16 ----------------
// No __syncthreads. Each WAVE owns an LDS slice and transposes one
// (64ch x 16hw) unit per iteration:
//   - lane l reads one full aligned 64B line: feat[pc*64+l][hw0..hw0+15]
//   - 16 conflict-free scalar LDS writes (stride TPW=17)
//   - wave_barrier; transposed LDS reads (2-way, free) + bf16 pack
//   - 4 x uint2 stores, each 512B fully coalesced
// 17 KB LDS/block -> 8 blocks/CU = 32 waves/CU, free-running (no phase lockstep).
__global__ __launch_bounds__(256) void nchw_to_blocked_v5(
    const float* __restrict__ feat,   // (B, 256, HW)
    uint2*       __restrict__ featT,  // (B*4 planes, HW, 16) uint2 (=64ch bf16)
    int nunits)                       // B*4*(HW/16)
{
    __shared__ float lds[4][64 * TPW];   // 4 waves x 4352 B = 17408 B
    int wid  = threadIdx.x >> 6;
    int lane = threadIdx.x & 63;
    float* Ws = lds[wid];

    int gwave  = blockIdx.x * 4 + wid;
    int nwaves = gridDim.x * 4;
    const int UPH = HW_ALL / 16;         // units per plane = 2500

    for (int u = gwave; u < nunits; u += nwaves) {
        int pc  = u / UPH;               // plane = b*4+cg
        int hw0 = (u - pc * UPH) * 16;

        // ---- load: one 64B line per lane ----
        const float4* src = (const float4*)(feat + ((size_t)pc * 64 + lane) * HW_ALL + hw0);
        float4 v0 = src[0];
        float4 v1 = src[1];
        float4 v2 = src[2];
        float4 v3 = src[3];

        // ---- LDS write: row=channel(lane), 16 floats @ stride TPW ----
        float* row = &Ws[lane * TPW];
        row[0]=v0.x;  row[1]=v0.y;  row[2]=v0.z;  row[3]=v0.w;
        row[4]=v1.x;  row[5]=v1.y;  row[6]=v1.z;  row[7]=v1.w;
        row[8]=v2.x;  row[9]=v2.y;  row[10]=v2.z; row[11]=v2.w;
        row[12]=v3.x; row[13]=v3.y; row[14]=v3.z; row[15]=v3.w;

        __builtin_amdgcn_wave_barrier();   // order write->read (intra-wave)

        // ---- transposed read + pack + store ----
        uint2* dst = featT + ((size_t)pc * HW_ALL + hw0) * 16;
        int q = lane & 15;                 // uint2 slot = channels 4q..4q+3
#pragma unroll
        for (int s = 0; s < 4; ++s) {
            int flat = s * 64 + lane;      // = hw_loc*16 + q
            int hw_loc = s * 4 + (lane >> 4);
            uint2 o;
            o.x = pack2_bf16(Ws[(4*q + 0) * TPW + hw_loc],
                             Ws[(4*q + 1) * TPW + hw_loc]);
            o.y = pack2_bf16(Ws[(4*q + 2) * TPW + hw_loc],
                             Ws[(4*q + 3) * TPW + hw_loc]);
            dst[flat] = o;                 // 64 lanes x 8B = 512B contiguous
        }

        __builtin_amdgcn_wave_barrier();   // order read->next write (WAR)
    }
}

// ---------------- Kernel 2: RoIAlign on blocked-NHWC bf16 (v4, UNCHANGED) ----
__global__ __launch_bounds__(256) void roialign_blocked_v4(
    const uint2* __restrict__ featT,   // (B*4, HW, 16) uint2
    const int*   __restrict__ rois,    // (N, 5)
    float*       __restrict__ out)     // (N, 256, 49)
{
    __shared__ float acc[64 * OUT_H * OUT_W];    // 12.5 KB
    const int H = FEAT_H, W = FEAT_W;
    int n  = blockIdx.x >> 2;
    int cg = blockIdx.x & 3;
    const int* r = rois + n * 5;
    int   b   = r[0];
    float x1f = (float)r[1];
    float y1f = (float)r[2];
    float dx  = (float)r[3] - x1f;
    float dy  = (float)r[4] - y1f;

    int t  = threadIdx.x;
    int cq = t & 15;
    int pg = t >> 4;                     // 0..15
    const uint2* fb = featT + ((size_t)(b * 4 + cg) * HW_ALL) * 16 + cq;

#define BFLO(u) __uint_as_float((u) << 16)
#define BFHI(u) __uint_as_float((u) & 0xffff0000u)

#pragma unroll
    for (int pi = 0; pi < 4; ++pi) {
        int p = (pi << 4) + pg;
        if (p < 49) {
            int jy = p / 7, jx = p % 7;
            float sy = y1f + ((float)jy * dy) / 6.0f;
            float sx = x1f + ((float)jx * dx) / 6.0f;
            float y0fl = floorf(sy), x0fl = floorf(sx);
            float wy = sy - y0fl,    wx = sx - x0fl;
            int y0  = min(max((int)y0fl, 0), H - 1);
            int y1i = min(y0 + 1, H - 1);
            int x0  = min(max((int)x0fl, 0), W - 1);
            int x1i = min(x0 + 1, W - 1);
            float omwy = 1.0f - wy, omwx = 1.0f - wx;
            float w00 = omwy * omwx, w01 = omwy * wx;
            float w10 = wy * omwx,   w11 = wy * wx;

            uint2 u00 = fb[(size_t)(y0  * W + x0 ) * 16];
            uint2 u01 = fb[(size_t)(y0  * W + x1i) * 16];
            uint2 u10 = fb[(size_t)(y1i * W + x0 ) * 16];
            uint2 u11 = fb[(size_t)(y1i * W + x1i) * 16];

            float r0 = BFLO(u00.x)*w00 + BFLO(u01.x)*w01 + BFLO(u10.x)*w10 + BFLO(u11.x)*w11;
            float r1 = BFHI(u00.x)*w00 + BFHI(u01.x)*w01 + BFHI(u10.x)*w10 + BFHI(u11.x)*w11;
            float r2 = BFLO(u00.y)*w00 + BFLO(u01.y)*w01 + BFLO(u10.y)*w10 + BFLO(u11.y)*w11;
            float r3 = BFHI(u00.y)*w00 + BFHI(u01.y)*w01 + BFHI(u10.y)*w10 + BFHI(u11.y)*w11;

            int c0 = cq << 2;            // local channel base 0..60
            acc[(c0 + 0) * 49 + p] = r0;
            acc[(c0 + 1) * 49 + p] = r1;
            acc[(c0 + 2) * 49 + p] = r2;
            acc[(c0 + 3) * 49 + p] = r3;
        }
    }
    __syncthreads();

    float* ob = out + ((size_t)n * 256 + cg * 64) * (OUT_H * OUT_W);
    const int total = 64 * OUT_H * OUT_W;
    for (int k = t; k < total; k += 256)
        ob[k] = acc[k];
}

// ---------------- Fallback: direct NCHW gather ----------------
__global__ __launch_bounds__(256) void roialign_direct(
    const float* __restrict__ feat, const int* __restrict__ rois,
    float* __restrict__ out, int C, int H, int W, int total)
{
    int idx = blockIdx.x * blockDim.x + threadIdx.x;
    if (idx >= total) return;
    int jx = idx % OUT_W;
    int t  = idx / OUT_W;
    int jy = t % OUT_H;
    t /= OUT_H;
    int c = t % C;
    int n = t / C;
    const int* r = rois + n * 5;
    int b = r[0];
    float x1 = (float)r[1], y1 = (float)r[2];
    float x2 = (float)r[3], y2 = (float)r[4];
    float sy = y1 + ((float)jy * (y2 - y1)) / (float)(OUT_H - 1);
    float sx = x1 + ((float)jx * (x2 - x1)) / (float)(OUT_W - 1);
    float y0f = floorf(sy), x0f = floorf(sx);
    float wy = sy - y0f, wx = sx - x0f;
    int y0  = min(max((int)y0f, 0), H - 1);
    int y1i = min(y0 + 1, H - 1);
    int x0  = min(max((int)x0f, 0), W - 1);
    int x1i = min(x0 + 1, W - 1);
    const float* fp = feat + ((size_t)b * C + c) * (size_t)(H * W);
    float v00 = fp[y0  * W + x0 ];
    float v01 = fp[y0  * W + x1i];
    float v10 = fp[y1i * W + x0 ];
    float v11 = fp[y1i * W + x1i];
    float omwy = 1.0f - wy, omwx = 1.0f - wx;
    out[idx] = v00 * omwy * omwx + v01 * omwy * wx
             + v10 * wy   * omwx + v11 * wy   * wx;
}

extern "C" void kernel_launch(void* const* d_in, const int* in_sizes, int n_in,
                              void* d_out, int out_size, void* d_ws, size_t ws_size,
                              hipStream_t stream)
{
    const float* feat = (const float*)d_in[0];
    const int*   rois = (const int*)d_in[1];
    float*       out  = (float*)d_out;

    int N  = in_sizes[1] / 5;                        // 512
    int C  = out_size / (N * OUT_H * OUT_W);         // 256
    int B  = in_sizes[0] / (C * HW_ALL);             // 4 when geometry matches

    size_t need = (size_t)B * HW_ALL * 256 * sizeof(__hip_bfloat16);  // 82 MB
    if (C == 256 && in_sizes[0] == B * 256 * HW_ALL && ws_size >= need) {
        uint2* featT = (uint2*)d_ws;
        int nunits = B * 4 * (HW_ALL / 16);          // 40000
        nchw_to_blocked_v5<<<2048, 256, 0, stream>>>(feat, featT, nunits);
        roialign_blocked_v4<<<N * 4, 256, 0, stream>>>(featT, rois, out);
    } else {
        int total = out_size;
        roialign_direct<<<(total + 255) / 256, 256, 0, stream>>>(
            feat, rois, out, C, FEAT_H, FEAT_W, total);
    }
}